// Round 8
// baseline (1053.572 us; speedup 1.0000x reference)
//
#include <hip/hip_runtime.h>
#include <hip/hip_cooperative_groups.h>
#include <math.h>
#include <stdint.h>

namespace cg = cooperative_groups;

constexpr int LL = 16384;
constexpr int NROW = 65536;             // N*L
constexpr int NPAIR = NROW * 8;         // 524288 (row,head) pairs
constexpr float EPS = 1e-6f;
constexpr float LN_EPS = 1e-5f;
constexpr size_t MIR_ELEMS = (size_t)NPAIR * 16;

// ---------------- fused cooperative layout ----------------
constexpr int GRID = 1024;              // 4 blocks/CU x 256 CUs; block owns 2x256 pairs
// finals
constexpr int F_KSUM = 0;               // [4][128]
constexpr int F_KN   = 512;             // [4][128]
constexpr int F_SS   = 1024;            // [4][8]
constexpr int F_QSUM = 1056;            // [4][128]
constexpr int F_QN   = 1568;            // [4][128]
constexpr int F_KV   = 2080;            // [4][2048]  (ends 10272)
// per-block partials (fully overwritten; no zeroing)
constexpr int P_A1 = 10272;                     // [1024][256] qsum|ksum
constexpr int P_A2 = P_A1 + 1024 * 256;         // [1024][128] qn
constexpr int P_KN = P_A2 + 1024 * 128;         // [1024][128] kn
constexpr int P_SS = P_KN + 1024 * 128;         // [1024][8]   ssum
constexpr int P_KV = P_SS + 1024 * 8;           // [1024][2048] KV
constexpr int FU_END = P_KV + 1024 * 2048;      // 2639904 floats
constexpr size_t FU_MIRQ = (size_t)FU_END * 4;
constexpr size_t FU_MIRK = FU_MIRQ + MIR_ELEMS * 2;
constexpr size_t WS_FUSED = FU_MIRK + MIR_ELEMS * 2;   // ~44.1 MB

// ---------------- fallback (round-7 proven path) layout ----------------
constexpr int FB_KSUM = 0;
constexpr int FB_KN   = 512;
constexpr int FB_SS   = 1024;
constexpr int FB_QSUM = 1056;
constexpr int FB_QN   = 1568;
constexpr int FB_KV   = 2080;
constexpr int FB_P_A1 = 10272;                     // [2048][256]
constexpr int FB_P_A2 = FB_P_A1 + 2048 * 256;      // [2048][128]
constexpr int FB_P_KN = FB_P_A2 + 2048 * 128;      // [2048][128]
constexpr int FB_P_SS = FB_P_KN + 2048 * 128;      // [2048][8]
constexpr int FB_P_KV = FB_P_SS + 2048 * 8;        // [2048][2048]
constexpr int FB_END = FB_P_KV + 2048 * 2048;
constexpr size_t FB_MIRQ = (size_t)FB_END * 4;
constexpr size_t FB_MIRK = FB_MIRQ + MIR_ELEMS * 2;
constexpr size_t FB_WS   = FB_MIRK + MIR_ELEMS * 2;   // ~54.7 MB

__device__ __forceinline__ float sigm(float x) { return __fdividef(1.f, 1.f + __expf(-x)); }
__device__ __forceinline__ unsigned short f2bf(float f) {
  uint32_t x = __float_as_uint(f);
  return (unsigned short)((x + 0x7FFFu + ((x >> 16) & 1u)) >> 16);
}
__device__ __forceinline__ float bf2f(unsigned short u) {
  return __uint_as_float(((uint32_t)u) << 16);
}

template <bool MIR>
__device__ __forceinline__ void load_sig(const unsigned short* mir, const float* fp, int p, float* r) {
  if (MIR) {
    const uint4* p4 = reinterpret_cast<const uint4*>(mir + (size_t)p * 16);
    uint4 a = p4[0], b = p4[1];
    uint32_t w[8] = {a.x, a.y, a.z, a.w, b.x, b.y, b.z, b.w};
#pragma unroll
    for (int j = 0; j < 8; ++j) {
      r[2 * j]     = bf2f((unsigned short)(w[j] & 0xFFFFu));
      r[2 * j + 1] = bf2f((unsigned short)(w[j] >> 16));
    }
  } else {
    const float4* p4 = reinterpret_cast<const float4*>(fp + (size_t)p * 16);
#pragma unroll
    for (int j = 0; j < 4; ++j) {
      float4 a = p4[j];
      r[4 * j] = sigm(a.x); r[4 * j + 1] = sigm(a.y);
      r[4 * j + 2] = sigm(a.z); r[4 * j + 3] = sigm(a.w);
    }
  }
}
__device__ __forceinline__ void load_raw16(const float* fp, int p, float* r) {
  const float4* p4 = reinterpret_cast<const float4*>(fp + (size_t)p * 16);
#pragma unroll
  for (int j = 0; j < 4; ++j) {
    float4 a = p4[j];
    r[4 * j] = a.x; r[4 * j + 1] = a.y; r[4 * j + 2] = a.z; r[4 * j + 3] = a.w;
  }
}
__device__ __forceinline__ void pack_store(unsigned short* dst, int p, const float* r) {
  union U { unsigned short u[8]; uint4 v; };
  U a, b;
#pragma unroll
  for (int j = 0; j < 8; ++j) { a.u[j] = f2bf(r[j]); b.u[j] = f2bf(r[8 + j]); }
  uint4* d = reinterpret_cast<uint4*>(dst + (size_t)p * 16);
  d[0] = a.v; d[1] = b.v;
}

// sums over the 8 lanes sharing (lane&7); every lane gets its group's sum
__device__ __forceinline__ float hred(float v) {
  v += __shfl_xor(v, 8, 64);
  v += __shfl_xor(v, 16, 64);
  v += __shfl_xor(v, 32, 64);
  return v;
}

__device__ __forceinline__ void stat_partial2(float* a, float* b, float* w4 /*[1024]*/,
                                              float* dst, int tid) {
  const int wave = tid >> 6, lane = tid & 63;
#pragma unroll
  for (int d = 0; d < 16; ++d) { a[d] = hred(a[d]); b[d] = hred(b[d]); }
  if (lane < 8) {
#pragma unroll
    for (int d = 0; d < 16; ++d) {
      w4[wave * 256 + lane * 16 + d] = a[d];
      w4[wave * 256 + 128 + lane * 16 + d] = b[d];
    }
  }
  __syncthreads();
  dst[tid] = w4[tid] + w4[256 + tid] + w4[512 + tid] + w4[768 + tid];
}

__device__ __forceinline__ void stat_partial1(float* a, float* w1 /*[512]*/,
                                              float* dst, int tid) {
  const int wave = tid >> 6, lane = tid & 63;
#pragma unroll
  for (int d = 0; d < 16; ++d) a[d] = hred(a[d]);
  if (lane < 8) {
#pragma unroll
    for (int d = 0; d < 16; ++d) w1[wave * 128 + lane * 16 + d] = a[d];
  }
  __syncthreads();
  if (tid < 128) dst[tid] = w1[tid] + w1[128 + tid] + w1[256 + tid] + w1[384 + tid];
}

// ================= fused cooperative kernel (stateless phases) =================
__global__ __launch_bounds__(256, 4) void k_fused(
    const float* Q, const float* K, const float* V,
    const float* gamma, const float* beta,
    float* ws, unsigned short* sQ, unsigned short* sK, float* out) {
  cg::grid_group grid = cg::this_grid();
  const int tid = threadIdx.x;
  const int blk = blockIdx.x;
  const int n = blk >> 8;          // both chunks of a block share n (512 chunks/n, 2/block)
  const int h = tid & 7;
  __shared__ __align__(16) float smem[9232];   // 36928 B -> 4 blocks/CU

  // ---- Phase 1: load+sigmoid, bf16 mirrors, qsum/ksum partials
  {
    float sq[16], sk[16];
#pragma unroll
    for (int d = 0; d < 16; ++d) { sq[d] = 0.f; sk[d] = 0.f; }
#pragma unroll
    for (int c = 0; c < 2; ++c) {
      const int p = (blk * 2 + c) * 256 + tid;
      float q[16];
      load_sig<false>(nullptr, Q, p, q);
      pack_store(sQ, p, q);
#pragma unroll
      for (int d = 0; d < 16; ++d) sq[d] += q[d];
      float k[16];
      load_sig<false>(nullptr, K, p, k);
      pack_store(sK, p, k);
#pragma unroll
      for (int d = 0; d < 16; ++d) sk[d] += k[d];
    }
    stat_partial2(sq, sk, smem, ws + P_A1 + (size_t)blk * 256, tid);
  }
  grid.sync();

  // ---- RedA: blocks 0..31 (4n x 8seg), 8 subs x 32 rows
  if (blk < 32) {
    const int rn = blk >> 3, seg = blk & 7;
    const int el = tid & 31, sub = tid >> 5;
    const float* src = ws + P_A1 + ((size_t)(rn * 256 + sub * 32)) * 256 + seg * 32 + el;
    float a = 0.f;
#pragma unroll
    for (int i = 0; i < 32; ++i) a += src[(size_t)i * 256];
    float* w = smem;
    w[tid] = a;
    __syncthreads();
    if (tid < 128) w[tid] += w[tid + 128];
    __syncthreads();
    if (tid < 64) w[tid] += w[tid + 64];
    __syncthreads();
    if (tid < 32) {
      const float v = w[tid] + w[tid + 32];
      const int elem = seg * 32 + tid;
      if (elem < 128) ws[F_QSUM + rn * 128 + elem] = v;
      else ws[F_KSUM + rn * 128 + (elem - 128)] = v;
    }
  }
  grid.sync();

  // ---- Phase 2: qn = sum_l q*nr partials (reads sQ mirror)
  {
    float* ksE = smem;
    float* w1 = smem + 128;
    if (tid < 128) ksE[tid] = ws[F_KSUM + n * 128 + tid] + EPS;
    __syncthreads();
    float qn[16];
#pragma unroll
    for (int d = 0; d < 16; ++d) qn[d] = 0.f;
#pragma unroll
    for (int c = 0; c < 2; ++c) {
      const int p = (blk * 2 + c) * 256 + tid;
      float q[16];
      load_sig<true>(sQ, nullptr, p, q);
      float dr = 0.f;
#pragma unroll
      for (int d = 0; d < 16; ++d) dr += (q[d] + EPS) * ksE[h * 16 + d];
      const float nr = __fdividef(1.f, dr);
#pragma unroll
      for (int d = 0; d < 16; ++d) qn[d] += q[d] * nr;
    }
    stat_partial1(qn, w1, ws + P_A2 + (size_t)blk * 128, tid);
  }
  grid.sync();

  // ---- RedB: blocks 0..15 (4n x 4seg)
  if (blk < 16) {
    const int rn = blk >> 2, seg = blk & 3;
    const int el = tid & 31, sub = tid >> 5;
    const float* src = ws + P_A2 + ((size_t)(rn * 256 + sub * 32)) * 128 + seg * 32 + el;
    float a = 0.f;
#pragma unroll
    for (int i = 0; i < 32; ++i) a += src[(size_t)i * 128];
    float* w = smem;
    w[tid] = a;
    __syncthreads();
    if (tid < 128) w[tid] += w[tid + 128];
    __syncthreads();
    if (tid < 64) w[tid] += w[tid + 64];
    __syncthreads();
    if (tid < 32) ws[F_QN + rn * 128 + seg * 32 + tid] = w[tid] + w[tid + 32];
  }
  grid.sync();

  // ---- Phase 3: nc/kn, w = exp(k.qnE), ssum, weighted-KV tile partials (2 tiles)
  {
    constexpr int RS = 132;
    float* qnE = smem;            // 128
    float* qsE = smem + 128;      // 128
    float* ssb = smem + 256;      // 8 (+8 pad)
    float* w1  = smem + 272;      // 512
    float* kwL = smem + 784;      // 32*132 (byte off 3136, 16-aligned)
    float* vL  = smem + 5008;     // 32*132 (byte off 20032, 16-aligned)
    if (tid < 128) {
      qnE[tid] = ws[F_QN + n * 128 + tid] + EPS;
      qsE[tid] = ws[F_QSUM + n * 128 + tid] + EPS;
    }
    if (tid < 8) ssb[tid] = 0.f;
    __syncthreads();
    const int ri = tid >> 3, lane = tid & 63, h2 = tid >> 5;
    const int d0 = ((tid >> 2) & 7) * 2;
    const int e0 = (tid & 3) * 4;
    float acc[2][4] = {{0.f, 0.f, 0.f, 0.f}, {0.f, 0.f, 0.f, 0.f}};
    float kn[16];
#pragma unroll
    for (int d = 0; d < 16; ++d) kn[d] = 0.f;
#pragma unroll
    for (int t = 0; t < 2; ++t) {
      const int p = (blk * 2 + t) * 256 + tid;
      float k[16], v[16];
      load_sig<true>(sK, nullptr, p, k);
      load_raw16(V, p, v);
      float dc = 0.f, ncr = 0.f;
#pragma unroll
      for (int d = 0; d < 16; ++d) {
        const float ke = k[d] + EPS;
        dc += ke * qsE[h * 16 + d];
        ncr += ke * qnE[h * 16 + d];
      }
      const float nc = __fdividef(1.f, dc);
#pragma unroll
      for (int d = 0; d < 16; ++d) kn[d] += k[d] * nc;
      const float w = __expf(ncr);   // ncr is O(1): no max-subtraction needed
      float sw = hred(w);
      if (lane < 8) atomicAdd(&ssb[lane], sw);   // LDS atomic, 8 addresses
      const int wb = ri * RS + h * 16;
#pragma unroll
      for (int d = 0; d < 16; ++d) { kwL[wb + d] = k[d] * w; vL[wb + d] = v[d]; }
      __syncthreads();
      const int rb0 = h2 * 16;
#pragma unroll 4
      for (int r = 0; r < 32; ++r) {
        const int rb = r * RS + rb0;
        const float2 kk = *reinterpret_cast<const float2*>(&kwL[rb + d0]);
        const float4 vv = *reinterpret_cast<const float4*>(&vL[rb + e0]);
        acc[0][0] += kk.x * vv.x; acc[0][1] += kk.x * vv.y;
        acc[0][2] += kk.x * vv.z; acc[0][3] += kk.x * vv.w;
        acc[1][0] += kk.y * vv.x; acc[1][1] += kk.y * vv.y;
        acc[1][2] += kk.y * vv.z; acc[1][3] += kk.y * vv.w;
      }
      __syncthreads();
    }
    stat_partial1(kn, w1, ws + P_KN + (size_t)blk * 128, tid);
    if (tid < 8) ws[P_SS + (size_t)blk * 8 + tid] = ssb[tid];
    float* pk = ws + P_KV + (size_t)blk * 2048;
    *reinterpret_cast<float4*>(pk + h2 * 256 + d0 * 16 + e0) =
        make_float4(acc[0][0], acc[0][1], acc[0][2], acc[0][3]);
    *reinterpret_cast<float4*>(pk + h2 * 256 + (d0 + 1) * 16 + e0) =
        make_float4(acc[1][0], acc[1][1], acc[1][2], acc[1][3]);
  }
  grid.sync();

  // ---- RedC: KV (blocks 0..255: 4n x 64seg), kn (256..271), ssum (272..275)
  if (blk < 256) {
    const int rn = blk >> 6, seg = blk & 63;
    const int el = tid & 31, sub = tid >> 5;
    const float* src = ws + P_KV + ((size_t)(rn * 256 + sub * 32)) * 2048 + seg * 32 + el;
    float a = 0.f;
#pragma unroll
    for (int i = 0; i < 32; ++i) a += src[(size_t)i * 2048];
    float* w = smem;
    w[tid] = a;
    __syncthreads();
    if (tid < 128) w[tid] += w[tid + 128];
    __syncthreads();
    if (tid < 64) w[tid] += w[tid + 64];
    __syncthreads();
    if (tid < 32) ws[F_KV + rn * 2048 + seg * 32 + tid] = w[tid] + w[tid + 32];
  } else if (blk < 272) {
    const int b2 = blk - 256;
    const int rn = b2 >> 2, seg = b2 & 3;
    const int el = tid & 31, sub = tid >> 5;
    const float* src = ws + P_KN + ((size_t)(rn * 256 + sub * 32)) * 128 + seg * 32 + el;
    float a = 0.f;
#pragma unroll
    for (int i = 0; i < 32; ++i) a += src[(size_t)i * 128];
    float* w = smem;
    w[tid] = a;
    __syncthreads();
    if (tid < 128) w[tid] += w[tid + 128];
    __syncthreads();
    if (tid < 64) w[tid] += w[tid + 64];
    __syncthreads();
    if (tid < 32) ws[F_KN + rn * 128 + seg * 32 + tid] = w[tid] + w[tid + 32];
  } else if (blk < 276) {
    const int rn = blk - 272;
    const int hh = tid & 7, sub = tid >> 3;   // 32 subs x 8 rows
    const float* src = ws + P_SS + ((size_t)(rn * 256 + sub * 8)) * 8 + hh;
    float a = 0.f;
#pragma unroll
    for (int i = 0; i < 8; ++i) a += src[(size_t)i * 8];
    float* w = smem;
    w[tid] = a;
    __syncthreads();
    if (tid < 128) w[tid] += w[tid + 128];
    __syncthreads();
    if (tid < 64) w[tid] += w[tid + 64];
    __syncthreads();
    if (tid < 32) w[tid] += w[tid + 32];
    __syncthreads();
    if (tid < 16) w[tid] += w[tid + 16];
    __syncthreads();
    if (tid < 8) ws[F_SS + rn * 8 + tid] = w[tid] + w[tid + 8];
  }
  grid.sync();

  // ---- Phase 4: x = q@kv * nr*nrr + v, LayerNorm, write out
  {
    float* kvs = smem;           // 8*260 = 2080 (pad 260: conflict-free by h)
    float* ksE = smem + 2080;    // 128
    float* knE = smem + 2208;    // 128
    float* gm  = smem + 2336;    // 16
    float* bt  = smem + 2352;    // 16
    float* ssE = smem + 2368;    // 8
    if (tid < 8) ssE[tid] = __fdividef((float)LL, ws[F_SS + n * 8 + tid]);
    if (tid >= 8 && tid < 136) {
      const int i = tid - 8;
      ksE[i] = ws[F_KSUM + n * 128 + i] + EPS;
      knE[i] = ws[F_KN + n * 128 + i] + EPS;
    }
    if (tid >= 136 && tid < 152) gm[tid - 136] = gamma[tid - 136];
    else if (tid >= 152 && tid < 168) bt[tid - 152] = beta[tid - 152];
    __syncthreads();
    for (int i = tid; i < 2048; i += 256) {
      const int hh = i >> 8, de = i & 255;
      kvs[hh * 260 + de] = ws[F_KV + n * 2048 + i] * ssE[hh];
    }
    __syncthreads();
#pragma unroll
    for (int c = 0; c < 2; ++c) {
      const int p = (blk * 2 + c) * 256 + tid;
      float q[16], v[16];
      load_sig<true>(sQ, nullptr, p, q);
      load_raw16(V, p, v);
      float dr = 0.f, drr = 0.f;
#pragma unroll
      for (int d = 0; d < 16; ++d) {
        const float qe = q[d] + EPS;
        dr += qe * ksE[h * 16 + d];
        drr += qe * knE[h * 16 + d];
      }
      const float sc = __fdividef(1.f, dr) * sigm(drr);
      float x[16];
#pragma unroll
      for (int e = 0; e < 16; ++e) x[e] = 0.f;
#pragma unroll
      for (int d = 0; d < 16; ++d) {
        const float qd = q[d];
        const float4* kr = reinterpret_cast<const float4*>(&kvs[h * 260 + d * 16]);
#pragma unroll
        for (int j = 0; j < 4; ++j) {
          float4 a = kr[j];
          x[4 * j] += qd * a.x; x[4 * j + 1] += qd * a.y;
          x[4 * j + 2] += qd * a.z; x[4 * j + 3] += qd * a.w;
        }
      }
#pragma unroll
      for (int e = 0; e < 16; ++e) x[e] = x[e] * sc + v[e];
      float mean = 0.f;
#pragma unroll
      for (int e = 0; e < 16; ++e) mean += x[e];
      mean *= (1.f / 16.f);
      float var = 0.f;
#pragma unroll
      for (int e = 0; e < 16; ++e) { const float t = x[e] - mean; var += t * t; }
      var *= (1.f / 16.f);
      const float inv = rsqrtf(var + LN_EPS);
#pragma unroll
      for (int e = 0; e < 16; ++e) x[e] = (x[e] - mean) * inv * gm[e] + bt[e];
      float4* op = reinterpret_cast<float4*>(out + (size_t)p * 16);
      op[0] = make_float4(x[0], x[1], x[2], x[3]);
      op[1] = make_float4(x[4], x[5], x[6], x[7]);
      op[2] = make_float4(x[8], x[9], x[10], x[11]);
      op[3] = make_float4(x[12], x[13], x[14], x[15]);
    }
  }
}

// ================= fallback: round-7 proven multi-kernel path =================
template <bool MIR>
__global__ __launch_bounds__(256) void fb_prep(const float* __restrict__ Q, const float* __restrict__ K,
                                               float* __restrict__ ws,
                                               unsigned short* __restrict__ sQ, unsigned short* __restrict__ sK) {
  const int tid = threadIdx.x;
  const int p = blockIdx.x * 256 + tid;
  __shared__ float w4[1024];
  float q[16], k[16];
  load_sig<false>(nullptr, Q, p, q);
  load_sig<false>(nullptr, K, p, k);
  if (MIR) { pack_store(sQ, p, q); pack_store(sK, p, k); }
  stat_partial2(q, k, w4, ws + FB_P_A1 + (size_t)blockIdx.x * 256, tid);
}

__global__ __launch_bounds__(256) void fb_redA(float* __restrict__ ws) {
  const int tid = threadIdx.x;
  const int n = blockIdx.x >> 3, seg = blockIdx.x & 7;
  const int el = tid & 31, sub = tid >> 5;
  __shared__ float w[256];
  const float* src = ws + FB_P_A1 + ((size_t)(n * 512 + sub * 64)) * 256 + seg * 32 + el;
  float a = 0.f;
#pragma unroll
  for (int i = 0; i < 64; ++i) a += src[(size_t)i * 256];
  w[tid] = a;
  __syncthreads();
  if (tid < 128) w[tid] += w[tid + 128];
  __syncthreads();
  if (tid < 64) w[tid] += w[tid + 64];
  __syncthreads();
  if (tid < 32) {
    const float v = w[tid] + w[tid + 32];
    const int elem = seg * 32 + tid;
    if (elem < 128) ws[FB_QSUM + n * 128 + elem] = v;
    else ws[FB_KSUM + n * 128 + (elem - 128)] = v;
  }
}

template <bool MIR>
__global__ __launch_bounds__(256) void fb_refq(const float* __restrict__ Q,
                                               const unsigned short* __restrict__ sQ,
                                               float* __restrict__ ws) {
  const int tid = threadIdx.x;
  const int p = blockIdx.x * 256 + tid;
  const int n = blockIdx.x >> 9;
  __shared__ float ksE[128];
  __shared__ float w1[512];
  if (tid < 128) ksE[tid] = ws[FB_KSUM + n * 128 + tid] + EPS;
  __syncthreads();
  const int h = tid & 7;
  float q[16];
  load_sig<MIR>(sQ, Q, p, q);
  float dr = 0.f;
#pragma unroll
  for (int d = 0; d < 16; ++d) dr += (q[d] + EPS) * ksE[h * 16 + d];
  const float nr = __fdividef(1.f, dr);
#pragma unroll
  for (int d = 0; d < 16; ++d) q[d] *= nr;
  stat_partial1(q, w1, ws + FB_P_A2 + (size_t)blockIdx.x * 128, tid);
}

__global__ __launch_bounds__(256) void fb_redB(float* __restrict__ ws) {
  const int tid = threadIdx.x;
  const int n = blockIdx.x >> 2, seg = blockIdx.x & 3;
  const int el = tid & 31, sub = tid >> 5;
  __shared__ float w[256];
  const float* src = ws + FB_P_A2 + ((size_t)(n * 512 + sub * 64)) * 128 + seg * 32 + el;
  float a = 0.f;
#pragma unroll
  for (int i = 0; i < 64; ++i) a += src[(size_t)i * 128];
  w[tid] = a;
  __syncthreads();
  if (tid < 128) w[tid] += w[tid + 128];
  __syncthreads();
  if (tid < 64) w[tid] += w[tid + 64];
  __syncthreads();
  if (tid < 32) ws[FB_QN + n * 128 + seg * 32 + tid] = w[tid] + w[tid + 32];
}

template <bool MIR>
__global__ __launch_bounds__(256) void fb_kv(const float* __restrict__ K, const float* __restrict__ V,
                                             const unsigned short* __restrict__ sK,
                                             float* __restrict__ ws) {
  const int tid = threadIdx.x;
  const int blk = blockIdx.x;
  const int n = blk >> 9;
  constexpr int RS = 132;
  __shared__ float qnE[128], qsE[128];
  __shared__ float ssb[8];
  __shared__ float w1[512];
  __shared__ __align__(16) float kwL[32 * RS];
  __shared__ __align__(16) float vL[32 * RS];
  if (tid < 128) {
    qnE[tid] = ws[FB_QN + n * 128 + tid] + EPS;
    qsE[tid] = ws[FB_QSUM + n * 128 + tid] + EPS;
  }
  if (tid < 8) ssb[tid] = 0.f;
  __syncthreads();
  const int h = tid & 7, ri = tid >> 3, lane = tid & 63;
  const int h2 = tid >> 5;
  const int d0 = ((tid >> 2) & 7) * 2;
  const int e0 = (tid & 3) * 4;
  const int p = blk * 256 + tid;
  float k[16], v[16];
  load_sig<MIR>(sK, K, p, k);
  load_raw16(V, p, v);
  float dc = 0.f, ncr = 0.f;
#pragma unroll
  for (int d = 0; d < 16; ++d) {
    const float ke = k[d] + EPS;
    dc += ke * qsE[h * 16 + d];
    ncr += ke * qnE[h * 16 + d];
  }
  const float nc = __fdividef(1.f, dc);
  float kn[16];
#pragma unroll
  for (int d = 0; d < 16; ++d) kn[d] = k[d] * nc;
  const float w = __expf(ncr);
  float sw = hred(w);
  if (lane < 8) atomicAdd(&ssb[lane], sw);
  const int wb = ri * RS + h * 16;
#pragma unroll
  for (int d = 0; d < 16; ++d) { kwL[wb + d] = k[d] * w; vL[wb + d] = v[d]; }
  __syncthreads();
  float acc[2][4] = {{0.f, 0.f, 0.f, 0.f}, {0.f, 0.f, 0.f, 0.f}};
  const int rb0 = h2 * 16;
#pragma unroll 4
  for (int r = 0; r < 32; ++r) {
    const int rb = r * RS + rb0;
    const float2 kk = *reinterpret_cast<const float2*>(&kwL[rb + d0]);
    const float4 vv = *reinterpret_cast<const float4*>(&vL[rb + e0]);
    acc[0][0] += kk.x * vv.x; acc[0][1] += kk.x * vv.y;
    acc[0][2] += kk.x * vv.z; acc[0][3] += kk.x * vv.w;
    acc[1][0] += kk.y * vv.x; acc[1][1] += kk.y * vv.y;
    acc[1][2] += kk.y * vv.z; acc[1][3] += kk.y * vv.w;
  }
  __syncthreads();
  stat_partial1(kn, w1, ws + FB_P_KN + (size_t)blk * 128, tid);
  if (tid < 8) ws[FB_P_SS + (size_t)blk * 8 + tid] = ssb[tid];
  float* pk = ws + FB_P_KV + (size_t)blk * 2048;
  *reinterpret_cast<float4*>(pk + h2 * 256 + d0 * 16 + e0) =
      make_float4(acc[0][0], acc[0][1], acc[0][2], acc[0][3]);
  *reinterpret_cast<float4*>(pk + h2 * 256 + (d0 + 1) * 16 + e0) =
      make_float4(acc[1][0], acc[1][1], acc[1][2], acc[1][3]);
}

__global__ __launch_bounds__(256) void fb_redC(float* __restrict__ ws) {
  const int tid = threadIdx.x;
  const int blk = blockIdx.x;
  __shared__ float w[256];
  if (blk < 256) {
    const int n = blk >> 6, seg = blk & 63;
    const int el = tid & 31, sub = tid >> 5;
    const float* src = ws + FB_P_KV + ((size_t)(n * 512 + sub * 64)) * 2048 + seg * 32 + el;
    float a = 0.f;
#pragma unroll
    for (int i = 0; i < 64; ++i) a += src[(size_t)i * 2048];
    w[tid] = a;
    __syncthreads();
    if (tid < 128) w[tid] += w[tid + 128];
    __syncthreads();
    if (tid < 64) w[tid] += w[tid + 64];
    __syncthreads();
    if (tid < 32) ws[FB_KV + n * 2048 + seg * 32 + tid] = w[tid] + w[tid + 32];
  } else if (blk < 272) {
    const int b2 = blk - 256;
    const int n = b2 >> 2, seg = b2 & 3;
    const int el = tid & 31, sub = tid >> 5;
    const float* src = ws + FB_P_KN + ((size_t)(n * 512 + sub * 64)) * 128 + seg * 32 + el;
    float a = 0.f;
#pragma unroll
    for (int i = 0; i < 64; ++i) a += src[(size_t)i * 128];
    w[tid] = a;
    __syncthreads();
    if (tid < 128) w[tid] += w[tid + 128];
    __syncthreads();
    if (tid < 64) w[tid] += w[tid + 64];
    __syncthreads();
    if (tid < 32) ws[FB_KN + n * 128 + seg * 32 + tid] = w[tid] + w[tid + 32];
  } else {
    const int n = blk - 272;
    const int hh = tid & 7, sub = tid >> 3;
    const float* src = ws + FB_P_SS + ((size_t)(n * 512 + sub * 16)) * 8 + hh;
    float a = 0.f;
#pragma unroll
    for (int i = 0; i < 16; ++i) a += src[(size_t)i * 8];
    w[tid] = a;
    __syncthreads();
    if (tid < 128) w[tid] += w[tid + 128];
    __syncthreads();
    if (tid < 64) w[tid] += w[tid + 64];
    __syncthreads();
    if (tid < 32) w[tid] += w[tid + 32];
    __syncthreads();
    if (tid < 16) w[tid] += w[tid + 16];
    __syncthreads();
    if (tid < 8) ws[FB_SS + n * 8 + tid] = w[tid] + w[tid + 8];
  }
}

template <bool MIR>
__global__ __launch_bounds__(256) void fb_out(const float* __restrict__ Q, const float* __restrict__ V,
                                              const unsigned short* __restrict__ sQ,
                                              const float* __restrict__ gamma, const float* __restrict__ beta,
                                              const float* __restrict__ ws, float* __restrict__ out) {
  const int tid = threadIdx.x;
  const int p = blockIdx.x * 256 + tid;
  const int n = blockIdx.x >> 9;
  __shared__ __align__(16) float kvs[8 * 260];
  __shared__ float ksE[128], knE[128], gm[16], bt[16], ssE[8];
  if (tid < 8) ssE[tid] = __fdividef((float)LL, ws[FB_SS + n * 8 + tid]);
  if (tid >= 8 && tid < 136) {
    const int i = tid - 8;
    ksE[i] = ws[FB_KSUM + n * 128 + i] + EPS;
    knE[i] = ws[FB_KN + n * 128 + i] + EPS;
  }
  if (tid >= 136 && tid < 152) gm[tid - 136] = gamma[tid - 136];
  else if (tid >= 152 && tid < 168) bt[tid - 152] = beta[tid - 152];
  __syncthreads();
  for (int i = tid; i < 2048; i += 256) {
    const int hh = i >> 8, de = i & 255;
    kvs[hh * 260 + de] = ws[FB_KV + n * 2048 + i] * ssE[hh];
  }
  __syncthreads();
  const int h = tid & 7;
  float q[16], v[16];
  load_sig<MIR>(sQ, Q, p, q);
  load_raw16(V, p, v);
  float dr = 0.f, drr = 0.f;
#pragma unroll
  for (int d = 0; d < 16; ++d) {
    const float qe = q[d] + EPS;
    dr += qe * ksE[h * 16 + d];
    drr += qe * knE[h * 16 + d];
  }
  const float sc = __fdividef(1.f, dr) * sigm(drr);
  float x[16];
#pragma unroll
  for (int e = 0; e < 16; ++e) x[e] = 0.f;
#pragma unroll
  for (int d = 0; d < 16; ++d) {
    const float qd = q[d];
    const float4* kr = reinterpret_cast<const float4*>(&kvs[h * 260 + d * 16]);
#pragma unroll
    for (int j = 0; j < 4; ++j) {
      float4 a = kr[j];
      x[4 * j] += qd * a.x; x[4 * j + 1] += qd * a.y;
      x[4 * j + 2] += qd * a.z; x[4 * j + 3] += qd * a.w;
    }
  }
#pragma unroll
  for (int e = 0; e < 16; ++e) x[e] = x[e] * sc + v[e];
  float mean = 0.f;
#pragma unroll
  for (int e = 0; e < 16; ++e) mean += x[e];
  mean *= (1.f / 16.f);
  float var = 0.f;
#pragma unroll
  for (int e = 0; e < 16; ++e) { const float t = x[e] - mean; var += t * t; }
  var *= (1.f / 16.f);
  const float inv = rsqrtf(var + LN_EPS);
#pragma unroll
  for (int e = 0; e < 16; ++e) x[e] = (x[e] - mean) * inv * gm[e] + bt[e];
  float4* op = reinterpret_cast<float4*>(out + (size_t)p * 16);
  op[0] = make_float4(x[0], x[1], x[2], x[3]);
  op[1] = make_float4(x[4], x[5], x[6], x[7]);
  op[2] = make_float4(x[8], x[9], x[10], x[11]);
  op[3] = make_float4(x[12], x[13], x[14], x[15]);
}

extern "C" void kernel_launch(void* const* d_in, const int* in_sizes, int n_in,
                              void* d_out, int out_size, void* d_ws, size_t ws_size,
                              hipStream_t stream) {
  const float* Q = (const float*)d_in[0];
  const float* K = (const float*)d_in[1];
  const float* V = (const float*)d_in[2];
  const float* gamma = (const float*)d_in[3];
  const float* beta = (const float*)d_in[4];
  float* ws = (float*)d_ws;
  float* out = (float*)d_out;

  // primary: single cooperative dispatch, stateless phases (no spills)
  bool ok = false;
  if (ws_size >= WS_FUSED) {
    unsigned short* sQ = (unsigned short*)((char*)d_ws + FU_MIRQ);
    unsigned short* sK = (unsigned short*)((char*)d_ws + FU_MIRK);
    void* args[] = {(void*)&Q, (void*)&K, (void*)&V, (void*)&gamma, (void*)&beta,
                    (void*)&ws, (void*)&sQ, (void*)&sK, (void*)&out};
    hipError_t err = hipLaunchCooperativeKernel(reinterpret_cast<void*>(&k_fused),
                                                dim3(GRID), dim3(256), args, 0, stream);
    ok = (err == hipSuccess);
    if (!ok) (void)hipGetLastError();   // clear sticky error before fallback
  }
  if (ok) return;

  // fallback: proven round-7 multi-kernel path
  unsigned short* sQ = (unsigned short*)((char*)d_ws + FB_MIRQ);
  unsigned short* sK = (unsigned short*)((char*)d_ws + FB_MIRK);
  const dim3 blk(256);
  const int gBig = NPAIR / 256;        // 2048

  if (ws_size >= FB_WS) {
    fb_prep<true><<<gBig, blk, 0, stream>>>(Q, K, ws, sQ, sK);
    fb_redA<<<32, blk, 0, stream>>>(ws);
    fb_refq<true><<<gBig, blk, 0, stream>>>(Q, sQ, ws);
    fb_redB<<<16, blk, 0, stream>>>(ws);
    fb_kv<true><<<gBig, blk, 0, stream>>>(K, V, sK, ws);
    fb_redC<<<276, blk, 0, stream>>>(ws);
    fb_out<true><<<gBig, blk, 0, stream>>>(Q, V, sQ, gamma, beta, ws, out);
  } else {
    fb_prep<false><<<gBig, blk, 0, stream>>>(Q, K, ws, nullptr, nullptr);
    fb_redA<<<32, blk, 0, stream>>>(ws);
    fb_refq<false><<<gBig, blk, 0, stream>>>(Q, nullptr, ws);
    fb_redB<<<16, blk, 0, stream>>>(ws);
    fb_kv<false><<<gBig, blk, 0, stream>>>(K, V, nullptr, ws);
    fb_redC<<<276, blk, 0, stream>>>(ws);
    fb_out<false><<<gBig, blk, 0, stream>>>(Q, V, nullptr, gamma, beta, ws, out);
  }
}

// Round 9
// 206.669 us; speedup vs baseline: 5.0979x; 5.0979x over previous
//
#include <hip/hip_runtime.h>
#include <math.h>
#include <stdint.h>

constexpr int LL = 16384;
constexpr int NROW = 65536;             // N*L
constexpr int NPAIR = NROW * 8;         // 524288 (row,head) pairs
constexpr float EPS = 1e-6f;
constexpr float LN_EPS = 1e-5f;
constexpr size_t MIR_ELEMS = (size_t)NPAIR * 16;

// ---------------- workspace layout (deterministic, no atomics; same as r7) ----------------
constexpr int F_KSUM = 0;               // [4][128]
constexpr int F_KN   = 512;             // [4][128]
constexpr int F_SS   = 1024;            // [4][8]
constexpr int F_QSUM = 1056;            // [4][128]
constexpr int F_QN   = 1568;            // [4][128]
constexpr int F_KV   = 2080;            // [4][2048]  (ends 10272)
constexpr int P_A1 = 10272;                     // [2048][256] qsum|ksum per prep block
constexpr int P_A2 = P_A1 + 2048 * 256;         // [2048][128] qn per refq block
constexpr int P_KN = P_A2 + 2048 * 128;         // [2048][128] kn per kv block
constexpr int P_SS = P_KN + 2048 * 128;         // [2048][8]   ssum per kv block
constexpr int P_KV = P_SS + 2048 * 8;           // [2048][2048] KV per kv block
constexpr int FLOAT_END = P_KV + 2048 * 2048;
constexpr size_t MIR_Q_BYTE = (size_t)FLOAT_END * 4;
constexpr size_t MIR_K_BYTE = MIR_Q_BYTE + MIR_ELEMS * 2;
constexpr size_t WS_FULL    = MIR_K_BYTE + MIR_ELEMS * 2;   // ~54.7 MB

// Mirror layout (quad-interleaved): for global pair p, quad j (4 floats each),
// mirror ushort4 index = p*4 + j. Writer and all readers share this convention.

__device__ __forceinline__ float sigm(float x) { return __fdividef(1.f, 1.f + __expf(-x)); }
__device__ __forceinline__ unsigned short f2bf(float f) {
  uint32_t x = __float_as_uint(f);
  return (unsigned short)((x + 0x7FFFu + ((x >> 16) & 1u)) >> 16);
}
__device__ __forceinline__ float bf2f(unsigned short u) {
  return __uint_as_float(((uint32_t)u) << 16);
}

// ---- lane-contiguous staging helpers (256 pairs per block) ----
// padded rows: pair-local row stride = 17 floats (coprime with 32 banks)

__device__ __forceinline__ void stage_f32(const float* src, int pairBase, float* lds, int tid) {
  const float4* s4 = reinterpret_cast<const float4*>(src) + (size_t)pairBase * 4;
#pragma unroll
  for (int i = 0; i < 4; ++i) {
    const int G = i * 256 + tid;                 // lane-contiguous 16B/lane
    const float4 v = s4[G];
    float* r = lds + (G >> 2) * 17 + (G & 3) * 4;
    r[0] = v.x; r[1] = v.y; r[2] = v.z; r[3] = v.w;
  }
}

__device__ __forceinline__ void stage_bf16(const unsigned short* mir, int pairBase, float* lds, int tid) {
  const uint2* s2 = reinterpret_cast<const uint2*>(mir) + (size_t)pairBase * 4;
#pragma unroll
  for (int i = 0; i < 4; ++i) {
    const int G = i * 256 + tid;                 // lane-contiguous 8B/lane
    const uint2 u = s2[G];
    float* r = lds + (G >> 2) * 17 + (G & 3) * 4;
    r[0] = bf2f((unsigned short)(u.x & 0xFFFFu)); r[1] = bf2f((unsigned short)(u.x >> 16));
    r[2] = bf2f((unsigned short)(u.y & 0xFFFFu)); r[3] = bf2f((unsigned short)(u.y >> 16));
  }
}

// pack thread's 16 floats to bf16 in LDS (9-uint padded rows), then lane-contiguous store.
// caller must __syncthreads() before (LDS buffer free) and after (before reuse).
__device__ __forceinline__ void mirror_store(unsigned short* mir, int pairBase, uint32_t* ldsu,
                                             const float* q, int tid) {
#pragma unroll
  for (int j = 0; j < 8; ++j)
    ldsu[tid * 9 + j] = (uint32_t)f2bf(q[2 * j]) | ((uint32_t)f2bf(q[2 * j + 1]) << 16);
  __syncthreads();
  uint2* d2 = reinterpret_cast<uint2*>(mir) + (size_t)pairBase * 4;
#pragma unroll
  for (int i = 0; i < 4; ++i) {
    const int G = i * 256 + tid;
    const int pl = G >> 2, qd = G & 3;
    d2[G] = make_uint2(ldsu[pl * 9 + qd * 2], ldsu[pl * 9 + qd * 2 + 1]);
  }
}

// sums over the 8 lanes sharing (lane&7); every lane gets its group's sum
__device__ __forceinline__ float hred(float v) {
  v += __shfl_xor(v, 8, 64);
  v += __shfl_xor(v, 16, 64);
  v += __shfl_xor(v, 32, 64);
  return v;
}

__device__ __forceinline__ void stat_partial2(float* a, float* b, float* w4 /*[1024]*/,
                                              float* dst, int tid) {
  const int wave = tid >> 6, lane = tid & 63;
#pragma unroll
  for (int d = 0; d < 16; ++d) { a[d] = hred(a[d]); b[d] = hred(b[d]); }
  if (lane < 8) {
#pragma unroll
    for (int d = 0; d < 16; ++d) {
      w4[wave * 256 + lane * 16 + d] = a[d];
      w4[wave * 256 + 128 + lane * 16 + d] = b[d];
    }
  }
  __syncthreads();
  dst[tid] = w4[tid] + w4[256 + tid] + w4[512 + tid] + w4[768 + tid];
}

__device__ __forceinline__ void stat_partial1(float* a, float* w1 /*[512]*/,
                                              float* dst, int tid) {
  const int wave = tid >> 6, lane = tid & 63;
#pragma unroll
  for (int d = 0; d < 16; ++d) a[d] = hred(a[d]);
  if (lane < 8) {
#pragma unroll
    for (int d = 0; d < 16; ++d) w1[wave * 128 + lane * 16 + d] = a[d];
  }
  __syncthreads();
  if (tid < 128) dst[tid] = w1[tid] + w1[128 + tid] + w1[256 + tid] + w1[384 + tid];
}

// Pass 1: sigmoid, bf16 mirrors, per-block qsum/ksum partials. 2048 blocks.
// All global I/O lane-contiguous via one 17.4 KB LDS buffer (8 blocks/CU).
template <bool MIR>
__global__ __launch_bounds__(256) void k_prep(const float* __restrict__ Q, const float* __restrict__ K,
                                              float* __restrict__ ws,
                                              unsigned short* __restrict__ sQ, unsigned short* __restrict__ sK) {
  const int tid = threadIdx.x;
  const int pairBase = blockIdx.x * 256;
  __shared__ __align__(16) float A[4352];
  uint32_t* Au = reinterpret_cast<uint32_t*>(A);
  float q[16], k[16];
  stage_f32(Q, pairBase, A, tid);
  __syncthreads();
#pragma unroll
  for (int d = 0; d < 16; ++d) q[d] = sigm(A[tid * 17 + d]);
  __syncthreads();
  if (MIR) {
    mirror_store(sQ, pairBase, Au, q, tid);
    __syncthreads();
  }
  stage_f32(K, pairBase, A, tid);
  __syncthreads();
#pragma unroll
  for (int d = 0; d < 16; ++d) k[d] = sigm(A[tid * 17 + d]);
  __syncthreads();
  if (MIR) {
    mirror_store(sK, pairBase, Au, k, tid);
    __syncthreads();
  }
  stat_partial2(q, k, A, ws + P_A1 + (size_t)blockIdx.x * 256, tid);
}

// redA: prep partials -> F_QSUM/F_KSUM. 32 blocks (4n x 8seg).
__global__ __launch_bounds__(256) void k_redA(float* __restrict__ ws) {
  const int tid = threadIdx.x;
  const int n = blockIdx.x >> 3, seg = blockIdx.x & 7;
  const int el = tid & 31, sub = tid >> 5;
  __shared__ float w[256];
  const float* src = ws + P_A1 + ((size_t)(n * 512 + sub * 64)) * 256 + seg * 32 + el;
  float a = 0.f;
#pragma unroll
  for (int i = 0; i < 64; ++i) a += src[(size_t)i * 256];
  w[tid] = a;
  __syncthreads();
  if (tid < 128) w[tid] += w[tid + 128];
  __syncthreads();
  if (tid < 64) w[tid] += w[tid + 64];
  __syncthreads();
  if (tid < 32) {
    const float v = w[tid] + w[tid + 32];
    const int elem = seg * 32 + tid;
    if (elem < 128) ws[F_QSUM + n * 128 + elem] = v;
    else ws[F_KSUM + n * 128 + (elem - 128)] = v;
  }
}

// Pass 2: qn = sum_l q*nr partials. 2048 blocks; staged sQ reads.
template <bool MIR>
__global__ __launch_bounds__(256) void k_refq(const float* __restrict__ Q,
                                              const unsigned short* __restrict__ sQ,
                                              float* __restrict__ ws) {
  const int tid = threadIdx.x;
  const int pairBase = blockIdx.x * 256;
  const int n = blockIdx.x >> 9;
  __shared__ __align__(16) float A[4352];
  __shared__ float ksE[128];
  __shared__ float w1[512];
  if (MIR) stage_bf16(sQ, pairBase, A, tid);
  else     stage_f32(Q, pairBase, A, tid);
  if (tid < 128) ksE[tid] = ws[F_KSUM + n * 128 + tid] + EPS;
  __syncthreads();
  const int h = tid & 7;
  float qv[16];
#pragma unroll
  for (int d = 0; d < 16; ++d) {
    const float t = A[tid * 17 + d];
    qv[d] = MIR ? t : sigm(t);
  }
  float dr = 0.f;
#pragma unroll
  for (int d = 0; d < 16; ++d) dr += (qv[d] + EPS) * ksE[h * 16 + d];
  const float nr = __fdividef(1.f, dr);
#pragma unroll
  for (int d = 0; d < 16; ++d) qv[d] *= nr;
  stat_partial1(qv, w1, ws + P_A2 + (size_t)blockIdx.x * 128, tid);
}

// redB: qn partials -> F_QN. 16 blocks (4n x 4seg).
__global__ __launch_bounds__(256) void k_redB(float* __restrict__ ws) {
  const int tid = threadIdx.x;
  const int n = blockIdx.x >> 2, seg = blockIdx.x & 3;
  const int el = tid & 31, sub = tid >> 5;
  __shared__ float w[256];
  const float* src = ws + P_A2 + ((size_t)(n * 512 + sub * 64)) * 128 + seg * 32 + el;
  float a = 0.f;
#pragma unroll
  for (int i = 0; i < 64; ++i) a += src[(size_t)i * 128];
  w[tid] = a;
  __syncthreads();
  if (tid < 128) w[tid] += w[tid + 128];
  __syncthreads();
  if (tid < 64) w[tid] += w[tid + 64];
  __syncthreads();
  if (tid < 32) ws[F_QN + n * 128 + seg * 32 + tid] = w[tid] + w[tid + 32];
}

// Pass 3: nc/kn, w = exp(k.qnE), ssum, weighted-KV tile partials. 2048 blocks.
// K and V staged DIRECTLY into the MAC tile (lane-contiguous global reads);
// each thread rescales its own tile row in place. LDS 36.9 KB -> 4 blocks/CU.
template <bool MIR>
__global__ __launch_bounds__(256) void k_kv(const float* __restrict__ K, const float* __restrict__ V,
                                            const unsigned short* __restrict__ sK,
                                            float* __restrict__ ws) {
  const int tid = threadIdx.x;
  const int blk = blockIdx.x;
  const int n = blk >> 9;
  constexpr int RS = 132;
  __shared__ float qnE[128], qsE[128];
  __shared__ float ssb[8];
  __shared__ __align__(16) float kwL[32 * RS];
  __shared__ __align__(16) float vL[32 * RS];
  const int pairBase = blk * 256;
  // stage K (raw or sigmoided-bf16) into kwL rows
  if (MIR) {
    const uint2* s2 = reinterpret_cast<const uint2*>(sK) + (size_t)pairBase * 4;
#pragma unroll
    for (int i = 0; i < 4; ++i) {
      const int G = i * 256 + tid;
      const uint2 u = s2[G];
      const int p = G >> 2;
      float* r = &kwL[(p >> 3) * RS + (p & 7) * 16 + (G & 3) * 4];
      r[0] = bf2f((unsigned short)(u.x & 0xFFFFu)); r[1] = bf2f((unsigned short)(u.x >> 16));
      r[2] = bf2f((unsigned short)(u.y & 0xFFFFu)); r[3] = bf2f((unsigned short)(u.y >> 16));
    }
  } else {
    const float4* s4 = reinterpret_cast<const float4*>(K) + (size_t)pairBase * 4;
#pragma unroll
    for (int i = 0; i < 4; ++i) {
      const int G = i * 256 + tid;
      const float4 v4 = s4[G];
      const int p = G >> 2;
      float* r = &kwL[(p >> 3) * RS + (p & 7) * 16 + (G & 3) * 4];
      r[0] = v4.x; r[1] = v4.y; r[2] = v4.z; r[3] = v4.w;
    }
  }
  // stage V into vL rows
  {
    const float4* s4 = reinterpret_cast<const float4*>(V) + (size_t)pairBase * 4;
#pragma unroll
    for (int i = 0; i < 4; ++i) {
      const int G = i * 256 + tid;
      const float4 v4 = s4[G];
      const int p = G >> 2;
      float* r = &vL[(p >> 3) * RS + (p & 7) * 16 + (G & 3) * 4];
      r[0] = v4.x; r[1] = v4.y; r[2] = v4.z; r[3] = v4.w;
    }
  }
  if (tid < 128) {
    qnE[tid] = ws[F_QN + n * 128 + tid] + EPS;
    qsE[tid] = ws[F_QSUM + n * 128 + tid] + EPS;
  }
  if (tid < 8) ssb[tid] = 0.f;
  __syncthreads();
  const int h = tid & 7, lane = tid & 63;
  const int h2 = tid >> 5;
  const int d0 = ((tid >> 2) & 7) * 2;
  const int e0 = (tid & 3) * 4;
  const int myrow = (tid >> 3) * RS + h * 16;
  float k[16];
#pragma unroll
  for (int d = 0; d < 16; ++d) {
    const float t = kwL[myrow + d];
    k[d] = MIR ? t : sigm(t);
  }
  float dc = 0.f, ncr = 0.f;
#pragma unroll
  for (int d = 0; d < 16; ++d) {
    const float ke = k[d] + EPS;
    dc += ke * qsE[h * 16 + d];
    ncr += ke * qnE[h * 16 + d];
  }
  const float nc = __fdividef(1.f, dc);
  float kn[16];
#pragma unroll
  for (int d = 0; d < 16; ++d) kn[d] = k[d] * nc;
  const float w = __expf(ncr);   // ncr is O(1): no max-subtraction needed
  float sw = hred(w);
  if (lane < 8) atomicAdd(&ssb[lane], sw);   // LDS atomic, 8 addresses
#pragma unroll
  for (int d = 0; d < 16; ++d) kwL[myrow + d] = k[d] * w;  // in-place rescale of own row
  __syncthreads();
  float acc[2][4] = {{0.f, 0.f, 0.f, 0.f}, {0.f, 0.f, 0.f, 0.f}};
  const int rb0 = h2 * 16;
#pragma unroll 4
  for (int r = 0; r < 32; ++r) {
    const int rb = r * RS + rb0;
    const float2 kk = *reinterpret_cast<const float2*>(&kwL[rb + d0]);
    const float4 vv = *reinterpret_cast<const float4*>(&vL[rb + e0]);
    acc[0][0] += kk.x * vv.x; acc[0][1] += kk.x * vv.y;
    acc[0][2] += kk.x * vv.z; acc[0][3] += kk.x * vv.w;
    acc[1][0] += kk.y * vv.x; acc[1][1] += kk.y * vv.y;
    acc[1][2] += kk.y * vv.z; acc[1][3] += kk.y * vv.w;
  }
  __syncthreads();
  // per-block partial writes (deterministic); reuse kwL as the stat scratch
  stat_partial1(kn, kwL, ws + P_KN + (size_t)blk * 128, tid);
  if (tid < 8) ws[P_SS + (size_t)blk * 8 + tid] = ssb[tid];
  float* pk = ws + P_KV + (size_t)blk * 2048;
  *reinterpret_cast<float4*>(pk + h2 * 256 + d0 * 16 + e0) =
      make_float4(acc[0][0], acc[0][1], acc[0][2], acc[0][3]);
  *reinterpret_cast<float4*>(pk + h2 * 256 + (d0 + 1) * 16 + e0) =
      make_float4(acc[1][0], acc[1][1], acc[1][2], acc[1][3]);
}

// redC: KV/kn/ssum partials -> finals. 276 blocks with role switch.
__global__ __launch_bounds__(256) void k_redC(float* __restrict__ ws) {
  const int tid = threadIdx.x;
  const int blk = blockIdx.x;
  __shared__ float w[256];
  if (blk < 256) {
    const int n = blk >> 6, seg = blk & 63;
    const int el = tid & 31, sub = tid >> 5;
    const float* src = ws + P_KV + ((size_t)(n * 512 + sub * 64)) * 2048 + seg * 32 + el;
    float a = 0.f;
#pragma unroll
    for (int i = 0; i < 64; ++i) a += src[(size_t)i * 2048];
    w[tid] = a;
    __syncthreads();
    if (tid < 128) w[tid] += w[tid + 128];
    __syncthreads();
    if (tid < 64) w[tid] += w[tid + 64];
    __syncthreads();
    if (tid < 32) ws[F_KV + n * 2048 + seg * 32 + tid] = w[tid] + w[tid + 32];
  } else if (blk < 272) {
    const int b2 = blk - 256;
    const int n = b2 >> 2, seg = b2 & 3;
    const int el = tid & 31, sub = tid >> 5;
    const float* src = ws + P_KN + ((size_t)(n * 512 + sub * 64)) * 128 + seg * 32 + el;
    float a = 0.f;
#pragma unroll
    for (int i = 0; i < 64; ++i) a += src[(size_t)i * 128];
    w[tid] = a;
    __syncthreads();
    if (tid < 128) w[tid] += w[tid + 128];
    __syncthreads();
    if (tid < 64) w[tid] += w[tid + 64];
    __syncthreads();
    if (tid < 32) ws[F_KN + n * 128 + seg * 32 + tid] = w[tid] + w[tid + 32];
  } else {
    const int n = blk - 272;
    const int hh = tid & 7, sub = tid >> 3;
    const float* src = ws + P_SS + ((size_t)(n * 512 + sub * 16)) * 8 + hh;
    float a = 0.f;
#pragma unroll
    for (int i = 0; i < 16; ++i) a += src[(size_t)i * 8];
    w[tid] = a;
    __syncthreads();
    if (tid < 128) w[tid] += w[tid + 128];
    __syncthreads();
    if (tid < 64) w[tid] += w[tid + 64];
    __syncthreads();
    if (tid < 32) w[tid] += w[tid + 32];
    __syncthreads();
    if (tid < 16) w[tid] += w[tid + 16];
    __syncthreads();
    if (tid < 8) ws[F_SS + n * 8 + tid] = w[tid] + w[tid + 8];
  }
}

// Pass 4: x = q@kv * nr*nrr + v, LayerNorm, write out. 2048 blocks.
// Staged sQ and V reads; staged lane-contiguous output store.
template <bool MIR>
__global__ __launch_bounds__(256) void k_out(const float* __restrict__ Q, const float* __restrict__ V,
                                             const unsigned short* __restrict__ sQ,
                                             const float* __restrict__ gamma, const float* __restrict__ beta,
                                             const float* __restrict__ ws, float* __restrict__ out) {
  const int tid = threadIdx.x;
  const int pairBase = blockIdx.x * 256;
  const int n = blockIdx.x >> 9;
  __shared__ __align__(16) float S[4352];
  __shared__ __align__(16) float kvs[8 * 260];  // pad 260 → conflict-free by h
  __shared__ float ksE[128], knE[128], gm[16], bt[16], ssE[8];
  if (MIR) stage_bf16(sQ, pairBase, S, tid);
  else     stage_f32(Q, pairBase, S, tid);
  if (tid < 8) ssE[tid] = __fdividef((float)LL, ws[F_SS + n * 8 + tid]);
  if (tid >= 8 && tid < 136) {
    const int i = tid - 8;
    ksE[i] = ws[F_KSUM + n * 128 + i] + EPS;
    knE[i] = ws[F_KN + n * 128 + i] + EPS;
  }
  if (tid >= 136 && tid < 152) gm[tid - 136] = gamma[tid - 136];
  else if (tid >= 152 && tid < 168) bt[tid - 152] = beta[tid - 152];
  __syncthreads();
  for (int i = tid; i < 2048; i += 256) {
    const int hh = i >> 8, de = i & 255;
    kvs[hh * 260 + de] = ws[F_KV + n * 2048 + i] * ssE[hh];
  }
  const int h = tid & 7;
  float q[16];
#pragma unroll
  for (int d = 0; d < 16; ++d) {
    const float t = S[tid * 17 + d];
    q[d] = MIR ? t : sigm(t);
  }
  __syncthreads();   // S reads done + kvs filled
  stage_f32(V, pairBase, S, tid);
  __syncthreads();
  float v[16];
#pragma unroll
  for (int d = 0; d < 16; ++d) v[d] = S[tid * 17 + d];
  float dr = 0.f, drr = 0.f;
#pragma unroll
  for (int d = 0; d < 16; ++d) {
    const float qe = q[d] + EPS;
    dr += qe * ksE[h * 16 + d];
    drr += qe * knE[h * 16 + d];
  }
  const float sc = __fdividef(1.f, dr) * sigm(drr);
  float x[16];
#pragma unroll
  for (int e = 0; e < 16; ++e) x[e] = 0.f;
#pragma unroll
  for (int d = 0; d < 16; ++d) {
    const float qd = q[d];
    const float4* kr = reinterpret_cast<const float4*>(&kvs[h * 260 + d * 16]);
#pragma unroll
    for (int j = 0; j < 4; ++j) {
      float4 a = kr[j];
      x[4 * j] += qd * a.x; x[4 * j + 1] += qd * a.y;
      x[4 * j + 2] += qd * a.z; x[4 * j + 3] += qd * a.w;
    }
  }
#pragma unroll
  for (int e = 0; e < 16; ++e) x[e] = x[e] * sc + v[e];
  float mean = 0.f;
#pragma unroll
  for (int e = 0; e < 16; ++e) mean += x[e];
  mean *= (1.f / 16.f);
  float var = 0.f;
#pragma unroll
  for (int e = 0; e < 16; ++e) { const float t = x[e] - mean; var += t * t; }
  var *= (1.f / 16.f);
  const float inv = rsqrtf(var + LN_EPS);
#pragma unroll
  for (int e = 0; e < 16; ++e) x[e] = (x[e] - mean) * inv * gm[e] + bt[e];
  // pack x into padded LDS rows, then lane-contiguous float4 store
#pragma unroll
  for (int d = 0; d < 16; ++d) S[tid * 17 + d] = x[d];
  __syncthreads();
  float4* o4 = reinterpret_cast<float4*>(out) + (size_t)pairBase * 4;
#pragma unroll
  for (int i = 0; i < 4; ++i) {
    const int G = i * 256 + tid;
    const float* r = &S[(G >> 2) * 17 + (G & 3) * 4];
    o4[G] = make_float4(r[0], r[1], r[2], r[3]);
  }
}

extern "C" void kernel_launch(void* const* d_in, const int* in_sizes, int n_in,
                              void* d_out, int out_size, void* d_ws, size_t ws_size,
                              hipStream_t stream) {
  const float* Q = (const float*)d_in[0];
  const float* K = (const float*)d_in[1];
  const float* V = (const float*)d_in[2];
  const float* gamma = (const float*)d_in[3];
  const float* beta = (const float*)d_in[4];
  float* ws = (float*)d_ws;
  float* out = (float*)d_out;
  unsigned short* sQ = (unsigned short*)((char*)d_ws + MIR_Q_BYTE);
  unsigned short* sK = (unsigned short*)((char*)d_ws + MIR_K_BYTE);

  const dim3 blk(256);
  const int gBig = NPAIR / 256;        // 2048

  if (ws_size >= WS_FULL) {
    k_prep<true><<<gBig, blk, 0, stream>>>(Q, K, ws, sQ, sK);
    k_redA<<<32, blk, 0, stream>>>(ws);
    k_refq<true><<<gBig, blk, 0, stream>>>(Q, sQ, ws);
    k_redB<<<16, blk, 0, stream>>>(ws);
    k_kv<true><<<gBig, blk, 0, stream>>>(K, V, sK, ws);
    k_redC<<<276, blk, 0, stream>>>(ws);
    k_out<true><<<gBig, blk, 0, stream>>>(Q, V, sQ, gamma, beta, ws, out);
  } else {
    k_prep<false><<<gBig, blk, 0, stream>>>(Q, K, ws, nullptr, nullptr);
    k_redA<<<32, blk, 0, stream>>>(ws);
    k_refq<false><<<gBig, blk, 0, stream>>>(Q, nullptr, ws);
    k_redB<<<16, blk, 0, stream>>>(ws);
    k_kv<false><<<gBig, blk, 0, stream>>>(K, V, nullptr, ws);
    k_redC<<<276, blk, 0, stream>>>(ws);
    k_out<false><<<gBig, blk, 0, stream>>>(Q, V, nullptr, gamma, beta, ws, out);
  }
}